// Round 8
// baseline (918.650 us; speedup 1.0000x reference)
//
#include <hip/hip_runtime.h>
#include <stdint.h>

#define E_ 8
#define S_ 8192
#define H_ 2048
#define F_ 8192
#define C_ 1024
#define OUTN (S_*H_)

typedef __bf16 bf16x8 __attribute__((ext_vector_type(8)));
typedef float  f32x4  __attribute__((ext_vector_type(4)));
typedef float  f32x16 __attribute__((ext_vector_type(16)));
typedef unsigned short us8 __attribute__((ext_vector_type(8)));

__device__ __forceinline__ unsigned short f2bf(float f) {
    union { float f; unsigned u; } v; v.f = f;
    unsigned r = (v.u + 0x7FFFu + ((v.u >> 16) & 1u)) >> 16;
    return (unsigned short)r;
}

__device__ __forceinline__ void gload16(const void* g, void* l) {
    auto gp = (const __attribute__((address_space(1))) void*)(unsigned long long)(uintptr_t)g;
    auto lp = (__attribute__((address_space(3))) void*)(unsigned int)(uintptr_t)l;
    __builtin_amdgcn_global_load_lds(gp, lp, 16, 0, 0);
}

#define SB() __builtin_amdgcn_sched_barrier(0)
#define BAR() do { SB(); __builtin_amdgcn_s_barrier(); SB(); } while(0)
#define DSR(d, a, o) asm volatile("ds_read_b128 %0, %1 offset:" #o : "=v"(d) : "v"(a))
#define WLGKM(n) do { asm volatile("s_waitcnt lgkmcnt(" #n ")" ::: "memory"); SB(); } while(0)
#define WVM(n)   do { asm volatile("s_waitcnt vmcnt(" #n ")"   ::: "memory"); SB(); } while(0)
#define MM16(accv, af, bf) accv = __builtin_amdgcn_mfma_f32_16x16x32_bf16(af, bf, accv, 0, 0, 0)
#define MM32(accv, af, bf) accv = __builtin_amdgcn_mfma_f32_32x32x16_bf16(af, bf, accv, 0, 0, 0)

// ---------------- zero d_out ----------------
__global__ void zero_kernel(float* __restrict__ o, int n) {
    int i = blockIdx.x * blockDim.x + threadIdx.x;
    int st = gridDim.x * blockDim.x;
    for (; i < n; i += st) o[i] = 0.f;
}

// ---------------- transpose + fp32->bf16: dst[e][n][k] = src[e][k][n] ----------------
__global__ __launch_bounds__(256)
void transpose_cvt(const float* __restrict__ src, unsigned short* __restrict__ dst,
                   int R, int Cc)
{
    __shared__ float t[64][65];
    int tilesR = R >> 6, tilesC = Cc >> 6;
    int per_e = tilesR * tilesC;
    int bid = blockIdx.x;
    int e  = bid / per_e;
    int rm = bid - e * per_e;
    int tc = rm / tilesR;
    int tr = rm - tc * tilesR;

    const float* s = src + (size_t)e * R * Cc + (size_t)(tr * 64) * Cc + tc * 64;
    int tid = threadIdx.x;
    int rr = tid >> 4;
    int cc = (tid & 15) << 2;
#pragma unroll
    for (int i = 0; i < 4; i++) {
        float4 v = *(const float4*)(s + (size_t)(rr + i * 16) * Cc + cc);
        t[rr + i * 16][cc + 0] = v.x;
        t[rr + i * 16][cc + 1] = v.y;
        t[rr + i * 16][cc + 2] = v.z;
        t[rr + i * 16][cc + 3] = v.w;
    }
    __syncthreads();
    int nl = tid >> 2;
    int kq = (tid & 3) << 4;
    us8 o0, o1;
#pragma unroll
    for (int i = 0; i < 8; i++) o0[i] = f2bf(t[kq + i][nl]);
#pragma unroll
    for (int i = 0; i < 8; i++) o1[i] = f2bf(t[kq + 8 + i][nl]);
    unsigned short* d = dst + (size_t)e * R * Cc + (size_t)(tc * 64 + nl) * R + tr * 64 + kq;
    *reinterpret_cast<us8*>(d)     = o0;
    *reinterpret_cast<us8*>(d + 8) = o1;
}

// ---------------- gating ----------------
__global__ __launch_bounds__(256)
void gating_kernel(const float* __restrict__ x, const float* __restrict__ wg,
                   int* __restrict__ expert_id, float* __restrict__ gate_tok,
                   float* __restrict__ gates_all)
{
    int lane = threadIdx.x & 63;
    int wid  = threadIdx.x >> 6;
    int s = blockIdx.x * 4 + wid;
    const float* xs = x + (size_t)s * H_;
    float p[8];
#pragma unroll
    for (int j = 0; j < 8; j++) p[j] = 0.f;
    for (int h = lane; h < H_; h += 64) {
        float xv = xs[h];
        const float4* w4 = (const float4*)(wg + (size_t)h * 8);
        float4 a = w4[0], b = w4[1];
        p[0] += xv * a.x; p[1] += xv * a.y; p[2] += xv * a.z; p[3] += xv * a.w;
        p[4] += xv * b.x; p[5] += xv * b.y; p[6] += xv * b.z; p[7] += xv * b.w;
    }
#pragma unroll
    for (int off = 32; off; off >>= 1) {
#pragma unroll
        for (int j = 0; j < 8; j++) p[j] += __shfl_xor(p[j], off);
    }
    if (lane == 0) {
        float mx = p[0];
#pragma unroll
        for (int j = 1; j < 8; j++) mx = fmaxf(mx, p[j]);
        float ex[8], sum = 0.f;
#pragma unroll
        for (int j = 0; j < 8; j++) { ex[j] = expf(p[j] - mx); sum += ex[j]; }
        float inv = 1.f / sum;
        int am = 0; float best = p[0];
#pragma unroll
        for (int j = 1; j < 8; j++) if (p[j] > best) { best = p[j]; am = j; }
        expert_id[s] = am;
        gate_tok[s]  = expf(best - mx) * inv;
        float* ga = gates_all + (size_t)s * 8;
#pragma unroll
        for (int j = 0; j < 8; j++) ga[j] = ex[j] * inv;
    }
}

// ---------------- single-block capacity scan + l_aux + exp_counts ----------------
__global__ __launch_bounds__(1024)
void scan_kernel(const int* __restrict__ expert_id,
                 const float* __restrict__ gate_tok,
                 const float* __restrict__ gates_all,
                 int* __restrict__ token_slot,
                 float* __restrict__ gate_slot,
                 float* __restrict__ out_tail)
{
    __shared__ unsigned long long wt0[16], wt1[16];
    __shared__ unsigned long long tot0s, tot1s;
    __shared__ float red[1024 * 8];

    int tid = threadIdx.x;
    for (int i = tid; i < E_ * C_; i += 1024) token_slot[i] = -1;

    int ids[8];
#pragma unroll
    for (int j = 0; j < 8; j++) ids[j] = expert_id[tid * 8 + j];

    unsigned long long c0 = 0, c1 = 0;
#pragma unroll
    for (int j = 0; j < 8; j++) {
        int e = ids[j];
        unsigned long long inc = 1ull << ((e & 3) * 16);
        if (e < 4) c0 += inc; else c1 += inc;
    }
    unsigned long long s0 = c0, s1 = c1;
    int lane = tid & 63, w = tid >> 6;
#pragma unroll
    for (int off = 1; off < 64; off <<= 1) {
        unsigned long long t0 = __shfl_up(s0, off);
        unsigned long long t1 = __shfl_up(s1, off);
        if (lane >= off) { s0 += t0; s1 += t1; }
    }
    if (lane == 63) { wt0[w] = s0; wt1[w] = s1; }
    __syncthreads();
    unsigned long long off0 = 0, off1 = 0;
    for (int i = 0; i < w; i++) { off0 += wt0[i]; off1 += wt1[i]; }
    unsigned long long p0 = off0 + s0 - c0;
    unsigned long long p1 = off1 + s1 - c1;

#pragma unroll
    for (int j = 0; j < 8; j++) {
        int stok = tid * 8 + j;
        int e = ids[j];
        int sh = (e & 3) * 16;
        int slot = (int)(((e < 4 ? p0 : p1) >> sh) & 0xFFFFull);
        if (slot < C_) {
            token_slot[e * C_ + slot] = stok;
            gate_slot[e * C_ + slot]  = gate_tok[stok];
        }
        if (e < 4) p0 += 1ull << sh; else p1 += 1ull << sh;
    }
    if (tid == 1023) { tot0s = off0 + s0; tot1s = off1 + s1; }

    float me[8];
#pragma unroll
    for (int e2 = 0; e2 < 8; e2++) me[e2] = 0.f;
#pragma unroll
    for (int j = 0; j < 8; j++) {
        const float* ga = gates_all + (size_t)(tid * 8 + j) * 8;
#pragma unroll
        for (int e2 = 0; e2 < 8; e2++) me[e2] += ga[e2];
    }
#pragma unroll
    for (int e2 = 0; e2 < 8; e2++) red[tid * 8 + e2] = me[e2];
    __syncthreads();
    for (int st = 512; st > 0; st >>= 1) {
        if (tid < st) {
#pragma unroll
            for (int e2 = 0; e2 < 8; e2++) red[tid * 8 + e2] += red[(tid + st) * 8 + e2];
        }
        __syncthreads();
    }
    if (tid == 0) {
        float laux = 0.f;
#pragma unroll
        for (int e2 = 0; e2 < 8; e2++) {
            unsigned long long tv = (e2 < 4) ? tot0s : tot1s;
            float cnt = (float)((tv >> ((e2 & 3) * 16)) & 0xFFFFull);
            laux += red[e2] * cnt;
            out_tail[1 + e2] = cnt;
        }
        out_tail[0] = laux * (8.f / (8192.f * 8192.f));
    }
}

// ---------------- gather dispatched rows (fp32 -> bf16) ----------------
__global__ __launch_bounds__(256)
void gather_kernel(const float* __restrict__ x, const int* __restrict__ token_slot,
                   unsigned short* __restrict__ disp)
{
    int slot = blockIdx.x;
    int tok = token_slot[slot];
    int t = threadIdx.x;
    us8* d = reinterpret_cast<us8*>(disp + (size_t)slot * H_ + t * 8);
    if (tok < 0) {
        us8 z;
#pragma unroll
        for (int i = 0; i < 8; i++) z[i] = 0;
        *d = z;
        return;
    }
    const float4* s4 = (const float4*)(x + (size_t)tok * H_ + t * 8);
    float4 a = s4[0], b = s4[1];
    us8 o;
    o[0] = f2bf(a.x); o[1] = f2bf(a.y); o[2] = f2bf(a.z); o[3] = f2bf(a.w);
    o[4] = f2bf(b.x); o[5] = f2bf(b.y); o[6] = f2bf(b.z); o[7] = f2bf(b.w);
    *d = o;
}

// ====== GEMM1: 256x256, 32x32x16 MFMA, R5 read-ahead schedule (single instantiation) ======
// A [E*1024][K] bf16, B [E][N][K] bf16. BM=BN=256, BK=64, 8 waves (2M x 4N),
// wave tile 128x64. LDS 128KiB dbuf, st_16x32-style swizzle (staging identical to R5).
// Frags: a[mi 0..3][ks 0..3] (32 rows x K=16 each), b[ni 0..1][ks], acc f32x16[4][2].
template<int K, int N>
__global__ __launch_bounds__(512, 2)
void gemm32(const unsigned short* __restrict__ A,
            const unsigned short* __restrict__ B,
            const float* __restrict__ bias,
            unsigned short* __restrict__ hout,
            int Mt, int Nt)
{
    __shared__ char lds[131072];
    constexpr int KB  = K * 2;
    constexpr int QG  = 64 * KB;
    constexpr int NTI = K / 64;

    int nwg = gridDim.x;
    int bid = blockIdx.x;
    int cpx = nwg >> 3;
    int wg  = (bid & 7) * cpx + (bid >> 3);
    int per_e = Mt * Nt;
    int e  = wg / per_e;
    int r  = wg - e * per_e;
    int nt = r / Mt;
    int mt = r - nt * Mt;

    int tid  = threadIdx.x;
    int lane = tid & 63;
    int wid  = tid >> 6;
    int wr = wid >> 2, wc = wid & 3;

    const char* Ag = (const char*)(A + ((size_t)e * 1024 + (size_t)mt * 256) * (size_t)K);
    const char* Bg = (const char*)(B + ((size_t)e * N    + (size_t)nt * 256) * (size_t)K);

    // staging source offset (inverse st_16x32 swizzle on global src) — identical to R5
    int r16s   = (tid >> 2) & 15;
    int scs    = ((tid & 3) * 16) ^ ((r16s & 8) << 2);
    int colblk = (tid >> 6) & 1;
    int rb0    = tid >> 7;
    int off0 = (rb0 * 16 + r16s) * KB + colblk * 64 + scs;
    int widb = wid * 1024;

    auto SQ = [&](int dstbyte, const char* src) {
        gload16(src + off0, (char*)lds + dstbyte + widb);
    };

    // ---- prologue staging: A(0),B(0)->buf0 ; A(1),B(1)->buf1 ----
#pragma unroll
    for (int j = 0; j < 4; j++) SQ(j * 8192,          Ag + j * QG);
#pragma unroll
    for (int j = 0; j < 4; j++) SQ(65536 + j * 8192,  Bg + j * QG);
#pragma unroll
    for (int j = 0; j < 4; j++) SQ(32768 + j * 8192,  Ag + j * QG + 128);
#pragma unroll
    for (int j = 0; j < 4; j++) SQ(98304 + j * 8192,  Bg + j * QG + 128);
    WVM(8);
    BAR();

    // 32x32 fragment read bases: row = lane&31 -> ((lane>>4)&1)*2048 + (lane&15)*64;
    // k-bytes = ks*32 + 16*(lane>>5), stored col = (kb&63) ^ ((lane&8)<<2); ks even/odd bases.
    int lcom = ((lane >> 4) & 1) * 2048 + (lane & 15) * 64 + 16 * (lane >> 5);
    int lbE  = lcom + ((lane & 8) << 2);
    int lbO  = lcom + (32 ^ ((lane & 8) << 2));
    unsigned aE = (unsigned)(uintptr_t)lds + wr * 16384 + lbE;
    unsigned aO = (unsigned)(uintptr_t)lds + wr * 16384 + lbO;
    unsigned bE = (unsigned)(uintptr_t)lds + 65536 + wc * 8192 + lbE;
    unsigned bO = (unsigned)(uintptr_t)lds + 65536 + wc * 8192 + lbO;

    bf16x8 a[4][4], b[2][4];

    // prologue reads: a[0..1][*], b[0][*] from buf0 (12 reads)
    DSR(a[0][0], aE, 0);    DSR(a[0][1], aO, 0);
    DSR(a[0][2], aE, 1024); DSR(a[0][3], aO, 1024);
    DSR(a[1][0], aE, 4096); DSR(a[1][1], aO, 4096);
    DSR(a[1][2], aE, 5120); DSR(a[1][3], aO, 5120);
    DSR(b[0][0], bE, 0);    DSR(b[0][1], bO, 0);
    DSR(b[0][2], bE, 1024); DSR(b[0][3], bO, 1024);

    f32x16 acc[4][2];
#pragma unroll
    for (int i = 0; i < 4; i++)
#pragma unroll
        for (int j = 0; j < 2; j++)
#pragma unroll
            for (int q = 0; q < 16; q++) acc[i][j][q] = 0.f;

    for (int t = 0; t < NTI; ++t) {
        int bsel = (t & 1) << 15;
        unsigned avE = aE + bsel, avO = aO + bsel;
        unsigned bvE = bE + bsel, bvO = bO + bsel;
        unsigned anE = avE ^ 32768, anO = avO ^ 32768;
        unsigned bnE = bvE ^ 32768, bnO = bvO ^ 32768;

        // ---- P0: read b[1][*]; lgkm(4); MFMA Q00 (mi01 x ni0) ----
        DSR(b[1][0], bvE, 4096); DSR(b[1][1], bvO, 4096);
        DSR(b[1][2], bvE, 5120); DSR(b[1][3], bvO, 5120);
        WLGKM(4);
        __builtin_amdgcn_s_setprio(1);
#pragma unroll
        for (int mi = 0; mi < 2; mi++)
#pragma unroll
            for (int ks = 0; ks < 4; ks++) MM32(acc[mi][0], a[mi][ks], b[0][ks]);
        __builtin_amdgcn_s_setprio(0);

        // ---- P1: read a[2..3][*]; lgkm(8); MFMA Q01 (mi01 x ni1) ----
        DSR(a[2][0], avE, 8192);  DSR(a[2][1], avO, 8192);
        DSR(a[2][2], avE, 9216);  DSR(a[2][3], avO, 9216);
        DSR(a[3][0], avE, 12288); DSR(a[3][1], avO, 12288);
        DSR(a[3][2], avE, 13312); DSR(a[3][3], avO, 13312);
        WLGKM(8);
        __builtin_amdgcn_s_setprio(1);
#pragma unroll
        for (int mi = 0; mi < 2; mi++)
#pragma unroll
            for (int ks = 0; ks < 4; ks++) MM32(acc[mi][1], a[mi][ks], b[1][ks]);
        __builtin_amdgcn_s_setprio(0);

        // ---- P2: lgkm(0); MFMA Q10 (mi23 x ni0); BAR ----
        WLGKM(0);
        __builtin_amdgcn_s_setprio(1);
#pragma unroll
        for (int mi = 2; mi < 4; mi++)
#pragma unroll
            for (int ks = 0; ks < 4; ks++) MM32(acc[mi][0], a[mi][ks], b[0][ks]);
        __builtin_amdgcn_s_setprio(0);
        BAR();

        // ---- P3: stage t+2; vmcnt; BAR; read a01,b0(t+1); MFMA Q11 (mi23 x ni1) ----
        if (t + 2 < NTI) {
            size_t ko = (size_t)(t + 2) * 128;
#pragma unroll
            for (int j = 0; j < 4; j++) SQ(bsel + j * 8192,         Ag + j * QG + ko);
#pragma unroll
            for (int j = 0; j < 4; j++) SQ(bsel + 65536 + j * 8192, Bg + j * QG + ko);
            WVM(8);
        } else {
            WVM(0);
        }
        BAR();
        if (t + 1 < NTI) {
            DSR(a[0][0], anE, 0);    DSR(a[0][1], anO, 0);
            DSR(a[0][2], anE, 1024); DSR(a[0][3], anO, 1024);
            DSR(a[1][0], anE, 4096); DSR(a[1][1], anO, 4096);
            DSR(a[1][2], anE, 5120); DSR(a[1][3], anO, 5120);
            DSR(b[0][0], bnE, 0);    DSR(b[0][1], bnO, 0);
            DSR(b[0][2], bnE, 1024); DSR(b[0][3], bnO, 1024);
        }
        __builtin_amdgcn_s_setprio(1);
#pragma unroll
        for (int mi = 2; mi < 4; mi++)
#pragma unroll
            for (int ks = 0; ks < 4; ks++) MM32(acc[mi][1], a[mi][ks], b[1][ks]);
        __builtin_amdgcn_s_setprio(0);
    }

    // ---- epilogue: D col = lane&31, row = (reg&3)+8*(reg>>2)+4*(lane>>5) [m74/m101] ----
    int colb = wc * 64 + (lane & 31);
    int rowb = wr * 128 + 4 * (lane >> 5);
    size_t rowg = (size_t)e * C_ + (size_t)mt * 256;
    float bb2[2];
    bb2[0] = bias[(size_t)e * N + nt * 256 + colb];
    bb2[1] = bias[(size_t)e * N + nt * 256 + colb + 32];
#pragma unroll
    for (int mi = 0; mi < 4; mi++) {
#pragma unroll
        for (int rr2 = 0; rr2 < 16; rr2++) {
            int row = rowb + mi * 32 + (rr2 & 3) + 8 * (rr2 >> 2);
            size_t rb = (rowg + (size_t)row) * (size_t)N + nt * 256 + colb;
#pragma unroll
            for (int ni = 0; ni < 2; ni++) {
                float v = acc[mi][ni][rr2] + bb2[ni];
                float u2 = 1.5957691216057308f * (v + 0.044715f * v * v * v);
                float gl = v * __frcp_rn(1.f + __expf(-u2));
                hout[rb + ni * 32] = f2bf(gl);
            }
        }
    }
}

// ====== GEMM2: 16x16x32 MFMA, R5 read-ahead schedule (R5-exact, EPI=1) ======
template<int K, int N>
__global__ __launch_bounds__(512, 2)
void gemm16(const unsigned short* __restrict__ A,
            const unsigned short* __restrict__ B,
            const float* __restrict__ bias,
            float* __restrict__ fout,
            const int* __restrict__ token_slot,
            const float* __restrict__ gate_slot,
            int Mt, int Nt)
{
    __shared__ char lds[131072];
    constexpr int KB  = K * 2;
    constexpr int QG  = 64 * KB;
    constexpr int NTI = K / 64;

    int nwg = gridDim.x;
    int bid = blockIdx.x;
    int cpx = nwg >> 3;
    int wg  = (bid & 7) * cpx + (bid >> 3);
    int per_e = Mt * Nt;
    int e  = wg / per_e;
    int r  = wg - e * per_e;
    int nt = r / Mt;
    int mt = r - nt * Mt;

    int tid  = threadIdx.x;
    int lane = tid & 63;
    int wid  = tid >> 6;
    int wr = wid >> 2, wc = wid & 3;

    const char* Ag = (const char*)(A + ((size_t)e * 1024 + (size_t)mt * 256) * (size_t)K);
    const char* Bg = (const char*)(B + ((size_t)e * N    + (size_t)nt * 256) * (size_t)K);

    int r16s   = (tid >> 2) & 15;
    int scs    = ((tid & 3) * 16) ^ ((r16s & 8) << 2);
    int colblk = (tid >> 6) & 1;
    int rb0    = tid >> 7;
    int off0 = (rb0 * 16 + r16s) * KB + colblk * 64 + scs;
    int widb = wid * 1024;

    int lread = (lane & 15) * 64 + (((lane >> 4) * 16) ^ ((lane & 8) << 2));

    auto SQ = [&](int dstbyte, const char* src) {
        gload16(src + off0, (char*)lds + dstbyte + widb);
    };

#pragma unroll
    for (int j = 0; j < 4; j++) SQ(j * 8192,          Ag + j * QG);
#pragma unroll
    for (int j = 0; j < 4; j++) SQ(65536 + j * 8192,  Bg + j * QG);
#pragma unroll
    for (int j = 0; j < 4; j++) SQ(32768 + j * 8192,  Ag + j * QG + 128);
#pragma unroll
    for (int j = 0; j < 4; j++) SQ(98304 + j * 8192,  Bg + j * QG + 128);
    WVM(8);
    BAR();

    unsigned a0 = (unsigned)(uintptr_t)lds + wr * 16384 + lread;
    unsigned b0 = (unsigned)(uintptr_t)lds + 65536 + (wc >> 1) * 16384 + (wc & 1) * 8192 + lread;

    bf16x8 alo[4][2], ahi[4][2], blo[2][2], bhi[2][2];

    DSR(alo[0][0], a0, 0);    DSR(alo[0][1], a0, 1024);
    DSR(alo[1][0], a0, 2048); DSR(alo[1][1], a0, 3072);
    DSR(alo[2][0], a0, 4096); DSR(alo[2][1], a0, 5120);
    DSR(alo[3][0], a0, 6144); DSR(alo[3][1], a0, 7168);
    DSR(blo[0][0], b0, 0);    DSR(blo[0][1], b0, 1024);
    DSR(blo[1][0], b0, 2048); DSR(blo[1][1], b0, 3072);

    f32x4 acc[8][4];
    f32x4 zv = {0.f, 0.f, 0.f, 0.f};
#pragma unroll
    for (int i = 0; i < 8; i++)
#pragma unroll
        for (int j = 0; j < 4; j++) acc[i][j] = zv;

    for (int t = 0; t < NTI; ++t) {
        int bsel = (t & 1) << 15;
        unsigned av  = a0 + bsel;
        unsigned bv  = b0 + bsel;
        unsigned avn = av ^ 32768;
        unsigned bvn = bv ^ 32768;

        DSR(bhi[0][0], bv, 4096); DSR(bhi[0][1], bv, 5120);
        DSR(bhi[1][0], bv, 6144); DSR(bhi[1][1], bv, 7168);
        WLGKM(4);
        __builtin_amdgcn_s_setprio(1);
#pragma unroll
        for (int mi = 0; mi < 4; mi++)
#pragma unroll
            for (int ni = 0; ni < 2; ni++) {
                MM16(acc[mi][ni], alo[mi][0], blo[ni][0]);
                MM16(acc[mi][ni], alo[mi][1], blo[ni][1]);
            }
        __builtin_amdgcn_s_setprio(0);

        DSR(ahi[0][0], av, 8192);  DSR(ahi[0][1], av, 9216);
        DSR(ahi[1][0], av, 10240); DSR(ahi[1][1], av, 11264);
        DSR(ahi[2][0], av, 12288); DSR(ahi[2][1], av, 13312);
        DSR(ahi[3][0], av, 14336); DSR(ahi[3][1], av, 15360);
        WLGKM(8);
        __builtin_amdgcn_s_setprio(1);
#pragma unroll
        for (int mi = 0; mi < 4; mi++)
#pragma unroll
            for (int ni = 0; ni < 2; ni++) {
                MM16(acc[mi][ni + 2], alo[mi][0], bhi[ni][0]);
                MM16(acc[mi][ni + 2], alo[mi][1], bhi[ni][1]);
            }
        __builtin_amdgcn_s_setprio(0);

        WLGKM(0);
        __builtin_amdgcn_s_setprio(1);
#pragma unroll
        for (int mi = 0; mi < 4; mi++)
#pragma unroll
            for (int ni = 0; ni < 2; ni++) {
                MM16(acc[mi + 4][ni], ahi[mi][0], blo[ni][0]);
                MM16(acc[mi + 4][ni], ahi[mi][1], blo[ni][1]);
            }
        __builtin_amdgcn_s_setprio(0);
        BAR();

        if (t + 2 < NTI) {
            size_t ko = (size_t)(t + 2) * 128;
#pragma unroll
            for (int j = 0; j < 4; j++) SQ(bsel + j * 8192,         Ag + j * QG + ko);
#pragma unroll
            for (int j = 0; j < 4; j++) SQ(bsel + 65536 + j * 8192, Bg + j * QG + ko);
            WVM(8);
        } else {
            WVM(0);
        }
        BAR();
        if (t + 1 < NTI) {
            DSR(alo[0][0], avn, 0);    DSR(alo[0][1], avn, 1024);
            DSR(alo[1][0], avn, 2048); DSR(alo[1][1], avn, 3072);
            DSR(alo[2][0], avn, 4096); DSR(alo[2][1], avn, 5120);
            DSR(alo[3][0], avn, 6144); DSR(alo[3][1], avn, 7168);
            DSR(blo[0][0], bvn, 0);    DSR(blo[0][1], bvn, 1024);
            DSR(blo[1][0], bvn, 2048); DSR(blo[1][1], bvn, 3072);
        }
        __builtin_amdgcn_s_setprio(1);
#pragma unroll
        for (int mi = 0; mi < 4; mi++)
#pragma unroll
            for (int ni = 0; ni < 2; ni++) {
                MM16(acc[mi + 4][ni + 2], ahi[mi][0], bhi[ni][0]);
                MM16(acc[mi + 4][ni + 2], ahi[mi][1], bhi[ni][1]);
            }
        __builtin_amdgcn_s_setprio(0);
    }

    int rbase = wr * 128 + (lane >> 4) * 4;
    int cbase = wc * 64 + (lane & 15);
    float bb4[4];
#pragma unroll
    for (int ni = 0; ni < 4; ni++)
        bb4[ni] = bias[(size_t)e * N + nt * 256 + cbase + ni * 16];
#pragma unroll
    for (int mi = 0; mi < 8; mi++) {
#pragma unroll
        for (int rr2 = 0; rr2 < 4; rr2++) {
            int c = mt * 256 + rbase + mi * 16 + rr2;
            int tok = token_slot[e * C_ + c];
            if (tok < 0) continue;
            float g = gate_slot[e * C_ + c];
            size_t rb = (size_t)tok * (size_t)N + nt * 256 + cbase;
#pragma unroll
            for (int ni = 0; ni < 4; ni++) {
                float v = (acc[mi][ni][rr2] + bb4[ni]) * g;
                fout[rb + ni * 16] = v;
            }
        }
    }
}

extern "C" void kernel_launch(void* const* d_in, const int* in_sizes, int n_in,
                              void* d_out, int out_size, void* d_ws, size_t ws_size,
                              hipStream_t stream)
{
    const float* x   = (const float*)d_in[0];
    const float* wgp = (const float*)d_in[1];
    const float* w1  = (const float*)d_in[2];
    const float* b1  = (const float*)d_in[3];
    const float* w2  = (const float*)d_in[4];
    const float* b2  = (const float*)d_in[5];
    float* out = (float*)d_out;

    char* ws = (char*)d_ws;
    unsigned short* w1t  = (unsigned short*)(ws);                    // 268435456 B
    unsigned short* w2t  = (unsigned short*)(ws + 268435456ull);     // 268435456 B
    unsigned short* disp = (unsigned short*)(ws + 536870912ull);     //  33554432 B
    unsigned short* hbuf = (unsigned short*)(ws + 570425344ull);     // 134217728 B
    int*   expert_id  = (int*)  (ws + 704643072ull);
    float* gate_tok   = (float*)(ws + 704675840ull);
    float* gates_all  = (float*)(ws + 704708608ull);
    int*   token_slot = (int*)  (ws + 704970752ull);
    float* gate_slot  = (float*)(ws + 705003520ull);

    zero_kernel<<<4096, 256, 0, stream>>>(out, out_size);
    transpose_cvt<<<8 * 32 * 128, 256, 0, stream>>>(w1, w1t, 2048, 8192);
    transpose_cvt<<<8 * 128 * 32, 256, 0, stream>>>(w2, w2t, 8192, 2048);
    gating_kernel<<<2048, 256, 0, stream>>>(x, wgp, expert_id, gate_tok, gates_all);
    scan_kernel<<<1, 1024, 0, stream>>>(expert_id, gate_tok, gates_all, token_slot, gate_slot, out + OUTN);
    gather_kernel<<<8192, 256, 0, stream>>>(x, token_slot, disp);
    gemm32<2048, 8192><<<1024, 512, 0, stream>>>(disp, w1t, b1, hbuf, 4, 32);
    gemm16<8192, 2048><<<256, 512, 0, stream>>>(hbuf, w2t, b2, out, token_slot, gate_slot, 4, 8);
}

// Round 9
// 888.775 us; speedup vs baseline: 1.0336x; 1.0336x over previous
//
#include <hip/hip_runtime.h>
#include <stdint.h>

#define E_ 8
#define S_ 8192
#define H_ 2048
#define F_ 8192
#define C_ 1024
#define OUTN (S_*H_)

typedef __bf16 bf16x8 __attribute__((ext_vector_type(8)));
typedef float  f32x4  __attribute__((ext_vector_type(4)));
typedef unsigned short us8 __attribute__((ext_vector_type(8)));

__device__ __forceinline__ unsigned short f2bf(float f) {
    union { float f; unsigned u; } v; v.f = f;
    unsigned r = (v.u + 0x7FFFu + ((v.u >> 16) & 1u)) >> 16;
    return (unsigned short)r;
}

__device__ __forceinline__ void gload16(const void* g, void* l) {
    auto gp = (const __attribute__((address_space(1))) void*)(unsigned long long)(uintptr_t)g;
    auto lp = (__attribute__((address_space(3))) void*)(unsigned int)(uintptr_t)l;
    __builtin_amdgcn_global_load_lds(gp, lp, 16, 0, 0);
}

#define SB() __builtin_amdgcn_sched_barrier(0)
#define BAR() do { SB(); __builtin_amdgcn_s_barrier(); SB(); } while(0)
#define DSR(d, a, o) asm volatile("ds_read_b128 %0, %1 offset:" #o : "=v"(d) : "v"(a))
#define WLGKM(n) do { asm volatile("s_waitcnt lgkmcnt(" #n ")" ::: "memory"); SB(); } while(0)
#define WVM(n)   do { asm volatile("s_waitcnt vmcnt(" #n ")"   ::: "memory"); SB(); } while(0)
#define MM16(accv, af, bf) accv = __builtin_amdgcn_mfma_f32_16x16x32_bf16(af, bf, accv, 0, 0, 0)

// ---------------- zero d_out (nontemporal: never device-re-read) ----------------
__global__ void zero_kernel(float* __restrict__ o, int n) {
    int i = blockIdx.x * blockDim.x + threadIdx.x;
    int st = gridDim.x * blockDim.x;
    for (; i < n; i += st) __builtin_nontemporal_store(0.f, &o[i]);
}

// ---------------- transpose + fp32->bf16: dst[e][n][k] = src[e][k][n] ----------------
__global__ __launch_bounds__(256)
void transpose_cvt(const float* __restrict__ src, unsigned short* __restrict__ dst,
                   int R, int Cc)
{
    __shared__ float t[64][65];
    int tilesR = R >> 6, tilesC = Cc >> 6;
    int per_e = tilesR * tilesC;
    int bid = blockIdx.x;
    int e  = bid / per_e;
    int rm = bid - e * per_e;
    int tc = rm / tilesR;
    int tr = rm - tc * tilesR;

    const float* s = src + (size_t)e * R * Cc + (size_t)(tr * 64) * Cc + tc * 64;
    int tid = threadIdx.x;
    int rr = tid >> 4;
    int cc = (tid & 15) << 2;
#pragma unroll
    for (int i = 0; i < 4; i++) {
        float4 v = *(const float4*)(s + (size_t)(rr + i * 16) * Cc + cc);
        t[rr + i * 16][cc + 0] = v.x;
        t[rr + i * 16][cc + 1] = v.y;
        t[rr + i * 16][cc + 2] = v.z;
        t[rr + i * 16][cc + 3] = v.w;
    }
    __syncthreads();
    int nl = tid >> 2;
    int kq = (tid & 3) << 4;
    us8 o0, o1;
#pragma unroll
    for (int i = 0; i < 8; i++) o0[i] = f2bf(t[kq + i][nl]);
#pragma unroll
    for (int i = 0; i < 8; i++) o1[i] = f2bf(t[kq + 8 + i][nl]);
    unsigned short* d = dst + (size_t)e * R * Cc + (size_t)(tc * 64 + nl) * R + tr * 64 + kq;
    *reinterpret_cast<us8*>(d)     = o0;
    *reinterpret_cast<us8*>(d + 8) = o1;
}

// ---------------- gating ----------------
__global__ __launch_bounds__(256)
void gating_kernel(const float* __restrict__ x, const float* __restrict__ wg,
                   int* __restrict__ expert_id, float* __restrict__ gate_tok,
                   float* __restrict__ gates_all)
{
    int lane = threadIdx.x & 63;
    int wid  = threadIdx.x >> 6;
    int s = blockIdx.x * 4 + wid;
    const float* xs = x + (size_t)s * H_;
    float p[8];
#pragma unroll
    for (int j = 0; j < 8; j++) p[j] = 0.f;
    for (int h = lane; h < H_; h += 64) {
        float xv = xs[h];
        const float4* w4 = (const float4*)(wg + (size_t)h * 8);
        float4 a = w4[0], b = w4[1];
        p[0] += xv * a.x; p[1] += xv * a.y; p[2] += xv * a.z; p[3] += xv * a.w;
        p[4] += xv * b.x; p[5] += xv * b.y; p[6] += xv * b.z; p[7] += xv * b.w;
    }
#pragma unroll
    for (int off = 32; off; off >>= 1) {
#pragma unroll
        for (int j = 0; j < 8; j++) p[j] += __shfl_xor(p[j], off);
    }
    if (lane == 0) {
        float mx = p[0];
#pragma unroll
        for (int j = 1; j < 8; j++) mx = fmaxf(mx, p[j]);
        float ex[8], sum = 0.f;
#pragma unroll
        for (int j = 0; j < 8; j++) { ex[j] = expf(p[j] - mx); sum += ex[j]; }
        float inv = 1.f / sum;
        int am = 0; float best = p[0];
#pragma unroll
        for (int j = 1; j < 8; j++) if (p[j] > best) { best = p[j]; am = j; }
        expert_id[s] = am;
        gate_tok[s]  = expf(best - mx) * inv;
        float* ga = gates_all + (size_t)s * 8;
#pragma unroll
        for (int j = 0; j < 8; j++) ga[j] = ex[j] * inv;
    }
}

// ---------------- single-block capacity scan + l_aux + exp_counts ----------------
__global__ __launch_bounds__(1024)
void scan_kernel(const int* __restrict__ expert_id,
                 const float* __restrict__ gate_tok,
                 const float* __restrict__ gates_all,
                 int* __restrict__ token_slot,
                 float* __restrict__ gate_slot,
                 float* __restrict__ out_tail)
{
    __shared__ unsigned long long wt0[16], wt1[16];
    __shared__ unsigned long long tot0s, tot1s;
    __shared__ float red[1024 * 8];

    int tid = threadIdx.x;
    for (int i = tid; i < E_ * C_; i += 1024) token_slot[i] = -1;

    int ids[8];
#pragma unroll
    for (int j = 0; j < 8; j++) ids[j] = expert_id[tid * 8 + j];

    unsigned long long c0 = 0, c1 = 0;
#pragma unroll
    for (int j = 0; j < 8; j++) {
        int e = ids[j];
        unsigned long long inc = 1ull << ((e & 3) * 16);
        if (e < 4) c0 += inc; else c1 += inc;
    }
    unsigned long long s0 = c0, s1 = c1;
    int lane = tid & 63, w = tid >> 6;
#pragma unroll
    for (int off = 1; off < 64; off <<= 1) {
        unsigned long long t0 = __shfl_up(s0, off);
        unsigned long long t1 = __shfl_up(s1, off);
        if (lane >= off) { s0 += t0; s1 += t1; }
    }
    if (lane == 63) { wt0[w] = s0; wt1[w] = s1; }
    __syncthreads();
    unsigned long long off0 = 0, off1 = 0;
    for (int i = 0; i < w; i++) { off0 += wt0[i]; off1 += wt1[i]; }
    unsigned long long p0 = off0 + s0 - c0;
    unsigned long long p1 = off1 + s1 - c1;

#pragma unroll
    for (int j = 0; j < 8; j++) {
        int stok = tid * 8 + j;
        int e = ids[j];
        int sh = (e & 3) * 16;
        int slot = (int)(((e < 4 ? p0 : p1) >> sh) & 0xFFFFull);
        if (slot < C_) {
            token_slot[e * C_ + slot] = stok;
            gate_slot[e * C_ + slot]  = gate_tok[stok];
        }
        if (e < 4) p0 += 1ull << sh; else p1 += 1ull << sh;
    }
    if (tid == 1023) { tot0s = off0 + s0; tot1s = off1 + s1; }

    float me[8];
#pragma unroll
    for (int e2 = 0; e2 < 8; e2++) me[e2] = 0.f;
#pragma unroll
    for (int j = 0; j < 8; j++) {
        const float* ga = gates_all + (size_t)(tid * 8 + j) * 8;
#pragma unroll
        for (int e2 = 0; e2 < 8; e2++) me[e2] += ga[e2];
    }
#pragma unroll
    for (int e2 = 0; e2 < 8; e2++) red[tid * 8 + e2] = me[e2];
    __syncthreads();
    for (int st = 512; st > 0; st >>= 1) {
        if (tid < st) {
#pragma unroll
            for (int e2 = 0; e2 < 8; e2++) red[tid * 8 + e2] += red[(tid + st) * 8 + e2];
        }
        __syncthreads();
    }
    if (tid == 0) {
        float laux = 0.f;
#pragma unroll
        for (int e2 = 0; e2 < 8; e2++) {
            unsigned long long tv = (e2 < 4) ? tot0s : tot1s;
            float cnt = (float)((tv >> ((e2 & 3) * 16)) & 0xFFFFull);
            laux += red[e2] * cnt;
            out_tail[1 + e2] = cnt;
        }
        out_tail[0] = laux * (8.f / (8192.f * 8192.f));
    }
}

// ---------------- gather dispatched rows (fp32 -> bf16) ----------------
__global__ __launch_bounds__(256)
void gather_kernel(const float* __restrict__ x, const int* __restrict__ token_slot,
                   unsigned short* __restrict__ disp)
{
    int slot = blockIdx.x;
    int tok = token_slot[slot];
    int t = threadIdx.x;
    us8* d = reinterpret_cast<us8*>(disp + (size_t)slot * H_ + t * 8);
    if (tok < 0) {
        us8 z;
#pragma unroll
        for (int i = 0; i < 8; i++) z[i] = 0;
        *d = z;
        return;
    }
    const float4* s4 = (const float4*)(x + (size_t)tok * H_ + t * 8);
    float4 a = s4[0], b = s4[1];
    us8 o;
    o[0] = f2bf(a.x); o[1] = f2bf(a.y); o[2] = f2bf(a.z); o[3] = f2bf(a.w);
    o[4] = f2bf(b.x); o[5] = f2bf(b.y); o[6] = f2bf(b.z); o[7] = f2bf(b.w);
    *d = o;
}

// ====== 256x256 bf16 GEMM, R5 read-ahead counted-lgkm schedule (known-good) ======
// EPI 0: hout = gelu(A@B+bias) bf16 (normal stores — hbuf is re-read by GEMM2)
// EPI 1: scattered fout = gate*(A@B+bias) (NONTEMPORAL stores — never device-re-read)
template<int EPI, int K, int N>
__global__ __launch_bounds__(512, 2)
void gemmra(const unsigned short* __restrict__ A,
            const unsigned short* __restrict__ B,
            const float* __restrict__ bias,
            unsigned short* __restrict__ hout,
            float* __restrict__ fout,
            const int* __restrict__ token_slot,
            const float* __restrict__ gate_slot,
            int Mt, int Nt)
{
    __shared__ char lds[131072];
    constexpr int KB  = K * 2;
    constexpr int QG  = 64 * KB;
    constexpr int NTI = K / 64;

    int nwg = gridDim.x;
    int bid = blockIdx.x;
    int cpx = nwg >> 3;
    int wg  = (bid & 7) * cpx + (bid >> 3);
    int per_e = Mt * Nt;
    int e  = wg / per_e;
    int r  = wg - e * per_e;
    int nt = r / Mt;
    int mt = r - nt * Mt;

    int tid  = threadIdx.x;
    int lane = tid & 63;
    int wid  = tid >> 6;
    int wr = wid >> 2, wc = wid & 3;

    const char* Ag = (const char*)(A + ((size_t)e * 1024 + (size_t)mt * 256) * (size_t)K);
    const char* Bg = (const char*)(B + ((size_t)e * N    + (size_t)nt * 256) * (size_t)K);

    int r16s   = (tid >> 2) & 15;
    int scs    = ((tid & 3) * 16) ^ ((r16s & 8) << 2);
    int colblk = (tid >> 6) & 1;
    int rb0    = tid >> 7;
    int off0 = (rb0 * 16 + r16s) * KB + colblk * 64 + scs;
    int widb = wid * 1024;

    int lread = (lane & 15) * 64 + (((lane >> 4) * 16) ^ ((lane & 8) << 2));

    auto SQ = [&](int dstbyte, const char* src) {
        gload16(src + off0, (char*)lds + dstbyte + widb);
    };

    // ---- prologue staging: A(0),B(0)->buf0 ; A(1),B(1)->buf1 ----
#pragma unroll
    for (int j = 0; j < 4; j++) SQ(j * 8192,          Ag + j * QG);
#pragma unroll
    for (int j = 0; j < 4; j++) SQ(65536 + j * 8192,  Bg + j * QG);
#pragma unroll
    for (int j = 0; j < 4; j++) SQ(32768 + j * 8192,  Ag + j * QG + 128);
#pragma unroll
    for (int j = 0; j < 4; j++) SQ(98304 + j * 8192,  Bg + j * QG + 128);
    WVM(8);
    BAR();

    unsigned a0 = (unsigned)(uintptr_t)lds + wr * 16384 + lread;
    unsigned b0 = (unsigned)(uintptr_t)lds + 65536 + (wc >> 1) * 16384 + (wc & 1) * 8192 + lread;

    bf16x8 alo[4][2], ahi[4][2], blo[2][2], bhi[2][2];

    DSR(alo[0][0], a0, 0);    DSR(alo[0][1], a0, 1024);
    DSR(alo[1][0], a0, 2048); DSR(alo[1][1], a0, 3072);
    DSR(alo[2][0], a0, 4096); DSR(alo[2][1], a0, 5120);
    DSR(alo[3][0], a0, 6144); DSR(alo[3][1], a0, 7168);
    DSR(blo[0][0], b0, 0);    DSR(blo[0][1], b0, 1024);
    DSR(blo[1][0], b0, 2048); DSR(blo[1][1], b0, 3072);

    f32x4 acc[8][4];
    f32x4 zv = {0.f, 0.f, 0.f, 0.f};
#pragma unroll
    for (int i = 0; i < 8; i++)
#pragma unroll
        for (int j = 0; j < 4; j++) acc[i][j] = zv;

    for (int t = 0; t < NTI; ++t) {
        int bsel = (t & 1) << 15;
        unsigned av  = a0 + bsel;
        unsigned bv  = b0 + bsel;
        unsigned avn = av ^ 32768;
        unsigned bvn = bv ^ 32768;

        // ---- P0: read bhi(t); lgkm(4); MFMA (lo,lo) ----
        DSR(bhi[0][0], bv, 4096); DSR(bhi[0][1], bv, 5120);
        DSR(bhi[1][0], bv, 6144); DSR(bhi[1][1], bv, 7168);
        WLGKM(4);
        __builtin_amdgcn_s_setprio(1);
#pragma unroll
        for (int mi = 0; mi < 4; mi++)
#pragma unroll
            for (int ni = 0; ni < 2; ni++) {
                MM16(acc[mi][ni], alo[mi][0], blo[ni][0]);
                MM16(acc[mi][ni], alo[mi][1], blo[ni][1]);
            }
        __builtin_amdgcn_s_setprio(0);

        // ---- P1: read ahi(t); lgkm(8); MFMA (lo,hi) ----
        DSR(ahi[0][0], av, 8192);  DSR(ahi[0][1], av, 9216);
        DSR(ahi[1][0], av, 10240); DSR(ahi[1][1], av, 11264);
        DSR(ahi[2][0], av, 12288); DSR(ahi[2][1], av, 13312);
        DSR(ahi[3][0], av, 14336); DSR(ahi[3][1], av, 15360);
        WLGKM(8);
        __builtin_amdgcn_s_setprio(1);
#pragma unroll
        for (int mi = 0; mi < 4; mi++)
#pragma unroll
            for (int ni = 0; ni < 2; ni++) {
                MM16(acc[mi][ni + 2], alo[mi][0], bhi[ni][0]);
                MM16(acc[mi][ni + 2], alo[mi][1], bhi[ni][1]);
            }
        __builtin_amdgcn_s_setprio(0);

        // ---- P2: lgkm(0); MFMA (hi,lo); BAR ----
        WLGKM(0);
        __builtin_amdgcn_s_setprio(1);
#pragma unroll
        for (int mi = 0; mi < 4; mi++)
#pragma unroll
            for (int ni = 0; ni < 2; ni++) {
                MM16(acc[mi + 4][ni], ahi[mi][0], blo[ni][0]);
                MM16(acc[mi + 4][ni], ahi[mi][1], blo[ni][1]);
            }
        __builtin_amdgcn_s_setprio(0);
        BAR();

        // ---- P3: stage t+2 -> buf(t); vmcnt; BAR; read alo,blo(t+1); MFMA (hi,hi) ----
        if (t + 2 < NTI) {
            size_t ko = (size_t)(t + 2) * 128;
#pragma unroll
            for (int j = 0; j < 4; j++) SQ(bsel + j * 8192,         Ag + j * QG + ko);
#pragma unroll
            for (int j = 0; j < 4; j++) SQ(bsel + 65536 + j * 8192, Bg + j * QG + ko);
            WVM(8);
        } else {
            WVM(0);
        }
        BAR();
        if (t + 1 < NTI) {
            DSR(alo[0][0], avn, 0);    DSR(alo[0][1], avn, 1024);
            DSR(alo[1][0], avn, 2048); DSR(alo[1][1], avn, 3072);
            DSR(alo[2][0], avn, 4096); DSR(alo[2][1], avn, 5120);
            DSR(alo[3][0], avn, 6144); DSR(alo[3][1], avn, 7168);
            DSR(blo[0][0], bvn, 0);    DSR(blo[0][1], bvn, 1024);
            DSR(blo[1][0], bvn, 2048); DSR(blo[1][1], bvn, 3072);
        }
        __builtin_amdgcn_s_setprio(1);
#pragma unroll
        for (int mi = 0; mi < 4; mi++)
#pragma unroll
            for (int ni = 0; ni < 2; ni++) {
                MM16(acc[mi + 4][ni + 2], ahi[mi][0], bhi[ni][0]);
                MM16(acc[mi + 4][ni + 2], ahi[mi][1], bhi[ni][1]);
            }
        __builtin_amdgcn_s_setprio(0);
    }

    // ---- epilogue ----
    int rbase = wr * 128 + (lane >> 4) * 4;
    int cbase = wc * 64 + (lane & 15);

    if (EPI == 0) {
        size_t rowg = (size_t)e * C_ + (size_t)mt * 256;
        float bb4[4];
#pragma unroll
        for (int ni = 0; ni < 4; ni++)
            bb4[ni] = bias[(size_t)e * N + nt * 256 + cbase + ni * 16];
#pragma unroll
        for (int mi = 0; mi < 8; mi++) {
#pragma unroll
            for (int rr2 = 0; rr2 < 4; rr2++) {
                int m = rbase + mi * 16 + rr2;
                size_t rb = (rowg + (size_t)m) * (size_t)N + nt * 256 + cbase;
#pragma unroll
                for (int ni = 0; ni < 4; ni++) {
                    float v = acc[mi][ni][rr2] + bb4[ni];
                    float u2 = 1.5957691216057308f * (v + 0.044715f * v * v * v);
                    float gl = v * __frcp_rn(1.f + __expf(-u2));
                    hout[rb + ni * 16] = f2bf(gl);
                }
            }
        }
    } else {
        float bb4[4];
#pragma unroll
        for (int ni = 0; ni < 4; ni++)
            bb4[ni] = bias[(size_t)e * N + nt * 256 + cbase + ni * 16];
#pragma unroll
        for (int mi = 0; mi < 8; mi++) {
#pragma unroll
            for (int rr2 = 0; rr2 < 4; rr2++) {
                int c = mt * 256 + rbase + mi * 16 + rr2;
                int tok = token_slot[e * C_ + c];
                if (tok < 0) continue;
                float g = gate_slot[e * C_ + c];
                size_t rb = (size_t)tok * (size_t)N + nt * 256 + cbase;
#pragma unroll
                for (int ni = 0; ni < 4; ni++) {
                    float v = (acc[mi][ni][rr2] + bb4[ni]) * g;
                    __builtin_nontemporal_store(v, &fout[rb + ni * 16]);
                }
            }
        }
    }
}

extern "C" void kernel_launch(void* const* d_in, const int* in_sizes, int n_in,
                              void* d_out, int out_size, void* d_ws, size_t ws_size,
                              hipStream_t stream)
{
    const float* x   = (const float*)d_in[0];
    const float* wgp = (const float*)d_in[1];
    const float* w1  = (const float*)d_in[2];
    const float* b1  = (const float*)d_in[3];
    const float* w2  = (const float*)d_in[4];
    const float* b2  = (const float*)d_in[5];
    float* out = (float*)d_out;

    char* ws = (char*)d_ws;
    unsigned short* w1t  = (unsigned short*)(ws);                    // 268435456 B
    unsigned short* w2t  = (unsigned short*)(ws + 268435456ull);     // 268435456 B
    unsigned short* disp = (unsigned short*)(ws + 536870912ull);     //  33554432 B
    unsigned short* hbuf = (unsigned short*)(ws + 570425344ull);     // 134217728 B
    int*   expert_id  = (int*)  (ws + 704643072ull);
    float* gate_tok   = (float*)(ws + 704675840ull);
    float* gates_all  = (float*)(ws + 704708608ull);
    int*   token_slot = (int*)  (ws + 704970752ull);
    float* gate_slot  = (float*)(ws + 705003520ull);

    zero_kernel<<<4096, 256, 0, stream>>>(out, out_size);
    // T2 FIRST, T1 LAST: w1t is the freshest 268 MB in L3 when GEMM1 streams it.
    transpose_cvt<<<8 * 128 * 32, 256, 0, stream>>>(w2, w2t, 8192, 2048);
    transpose_cvt<<<8 * 32 * 128, 256, 0, stream>>>(w1, w1t, 2048, 8192);
    gating_kernel<<<2048, 256, 0, stream>>>(x, wgp, expert_id, gate_tok, gates_all);
    scan_kernel<<<1, 1024, 0, stream>>>(expert_id, gate_tok, gates_all, token_slot, gate_slot, out + OUTN);
    gather_kernel<<<8192, 256, 0, stream>>>(x, token_slot, disp);
    gemmra<0, 2048, 8192><<<1024, 512, 0, stream>>>(disp, w1t, b1, hbuf, nullptr, nullptr, nullptr, 4, 32);
    gemmra<1, 8192, 2048><<<256, 512, 0, stream>>>(hbuf, w2t, b2, nullptr, out, token_slot, gate_slot, 4, 8);
}